// Round 2
// baseline (309.176 us; speedup 1.0000x reference)
//
#include <hip/hip_runtime.h>
#include <math.h>

// Problem constants
#define NB    8
#define CIMG  64
#define HH    256
#define WW    256
#define NL    68
#define NP    136          // 2*NL
#define JD    128          // hidden dim
#define NSYS  71           // 68 + 3
#define NCHK  32           // K1 split-K chunks
#define CHUNK4 1536        // float4 per chunk (6144 floats)
#define ROW4  49152        // float4 per K-row (196608/4)

// d_out (f32) layout: warped [0, 33554432), pred [33554432, +1088), norm at 33555520
#define OUT_PRED 33554432
#define OUT_NORM 33555520

// d_ws (float) layout
#define WS_PART 0          // 32*128*8 = 32768 floats
#define WS_NORM 32768      // 8 floats (per-batch sum of disp^2)
#define WS_DST  32784      // 8*136 floats (control points, y/x interleaved)
#define WS_WV   33920      // 8*142 floats (w[68][2] then v[3][2] per batch)

// ---------------------------------------------------------------- K1: h partials
__global__ __launch_bounds__(256) void k1_gemv(const float* __restrict__ x,
                                               const float* __restrict__ W1,
                                               float* __restrict__ part) {
  const int jg  = blockIdx.x;   // 0..31 : group of 4 output rows
  const int ch  = blockIdx.y;   // 0..31 : K chunk
  const int tid = threadIdx.x;
  const float4* __restrict__ xv = (const float4*)x;
  const float4* __restrict__ wv = (const float4*)W1;

  float acc[4][8];
#pragma unroll
  for (int a = 0; a < 4; ++a)
#pragma unroll
    for (int b = 0; b < 8; ++b) acc[a][b] = 0.f;

  const int base = ch * CHUNK4;
#pragma unroll
  for (int it = 0; it < 6; ++it) {
    const int k4 = base + it * 256 + tid;
    float4 w[4];
#pragma unroll
    for (int jj = 0; jj < 4; ++jj)
      w[jj] = wv[(size_t)(jg * 4 + jj) * ROW4 + k4];
#pragma unroll
    for (int b = 0; b < 8; ++b) {
      const float4 xr = xv[(size_t)b * ROW4 + k4];
#pragma unroll
      for (int jj = 0; jj < 4; ++jj) {
        acc[jj][b] = fmaf(w[jj].x, xr.x, acc[jj][b]);
        acc[jj][b] = fmaf(w[jj].y, xr.y, acc[jj][b]);
        acc[jj][b] = fmaf(w[jj].z, xr.z, acc[jj][b]);
        acc[jj][b] = fmaf(w[jj].w, xr.w, acc[jj][b]);
      }
    }
  }
  // wave64 reduction
#pragma unroll
  for (int jj = 0; jj < 4; ++jj)
#pragma unroll
    for (int b = 0; b < 8; ++b) {
      float v = acc[jj][b];
      for (int o = 32; o > 0; o >>= 1) v += __shfl_down(v, o, 64);
      acc[jj][b] = v;
    }
  __shared__ float sred[4][32];
  const int lane = tid & 63, wid = tid >> 6;
  if (lane == 0) {
#pragma unroll
    for (int jj = 0; jj < 4; ++jj)
#pragma unroll
      for (int b = 0; b < 8; ++b) sred[wid][jj * 8 + b] = acc[jj][b];
  }
  __syncthreads();
  if (tid < 32) {
    const float s = sred[0][tid] + sred[1][tid] + sred[2][tid] + sred[3][tid];
    const int jj = tid >> 3, b = tid & 7;
    part[((size_t)ch * JD + jg * 4 + jj) * 8 + b] = s;
  }
}

// -------------------------------------------- K2: landmarks + TPS solve (1 block/batch)
__global__ __launch_bounds__(256) void k2_land_solve(
    const float* __restrict__ part, const float* __restrict__ scales,
    const float* __restrict__ lmean, const float* __restrict__ b1,
    const float* __restrict__ W2, const float* __restrict__ b2,
    const float* __restrict__ W3, const float* __restrict__ b3,
    float* __restrict__ out, float* __restrict__ ws) {
  const int b = blockIdx.x, tid = threadIdx.x;
  __shared__ float  s_h[JD];
  __shared__ float  s_dst[NP];
  __shared__ float  s_disp[NP];
  __shared__ double M[NSYS][NSYS + 3];   // cols 0..70 = matrix, 71..72 = rhs
  __shared__ double s_xs[2][NSYS];
  __shared__ int    s_perm[NSYS], s_used[NSYS], s_piv;

  // h[b][j] = b1[j] + sum_chunks part
  if (tid < JD) {
    float s = b1[tid];
    for (int c = 0; c < NCHK; ++c) s += part[((size_t)c * JD + tid) * 8 + b];
    s_h[tid] = s;
  }
  __syncthreads();

  // pred / disp
  if (tid < NP) {
    const float4* w2 = (const float4*)(W2 + (size_t)tid * JD);
    const float4* w3 = (const float4*)(W3 + (size_t)tid * JD);
    float a2 = 0.f, a3 = 0.f;
#pragma unroll 8
    for (int i = 0; i < 32; ++i) {
      const float4 u = w2[i], v = w3[i];
      const float h0 = s_h[4 * i], h1 = s_h[4 * i + 1];
      const float h2 = s_h[4 * i + 2], h3 = s_h[4 * i + 3];
      a2 = fmaf(u.x, h0, fmaf(u.y, h1, fmaf(u.z, h2, fmaf(u.w, h3, a2))));
      a3 = fmaf(v.x, h0, fmaf(v.y, h1, fmaf(v.z, h2, fmaf(v.w, h3, a3))));
    }
    const float pred = a2 + b2[tid] + lmean[tid];
    const float disp = (a3 + b3[tid]) * scales[b];
    out[OUT_PRED + b * NP + tid] = pred;
    s_dst[tid]  = pred + disp;   // train points (dst)
    s_disp[tid] = disp;          // flows (dst - src)
  }
  __syncthreads();

  // per-batch sum of squared disp (norm finalized in K3)
  if (tid < 64) {
    float s = 0.f;
    for (int i = tid; i < NP; i += 64) { const float d = s_disp[i]; s += d * d; }
    for (int o = 32; o > 0; o >>= 1) s += __shfl_down(s, o, 64);
    if (tid == 0) ws[WS_NORM + b] = s;
  }
  if (tid < NP) ws[WS_DST + b * NP + tid] = s_dst[tid];
  __syncthreads();

  // build augmented system [[A,B],[B^T,0] | rhs] in f64
  for (int e = tid; e < NSYS * (NSYS + 2); e += 256) {
    const int r = e / (NSYS + 2), c = e - r * (NSYS + 2);
    double val;
    if (r < NL) {
      if (c < NL) {
        const double dy = (double)s_dst[2 * r]     - (double)s_dst[2 * c];
        const double dx = (double)s_dst[2 * r + 1] - (double)s_dst[2 * c + 1];
        const double d2 = dy * dy + dx * dx;
        const double ph = 0.5 * d2 * log(fmax(d2, 1e-10));
        val = (r == c) ? ph + 1e-6 : ph;
      } else if (c == NL)     val = (double)s_dst[2 * r];
      else if (c == NL + 1)   val = (double)s_dst[2 * r + 1];
      else if (c == NL + 2)   val = 1.0;
      else                    val = (double)s_disp[2 * r + (c - NSYS)];  // rhs
    } else {
      if (c < NL) {
        const int q = r - NL;
        val = (q == 0) ? (double)s_dst[2 * c] : (q == 1) ? (double)s_dst[2 * c + 1] : 1.0;
      } else val = 0.0;
    }
    M[r][c] = val;
  }
  if (tid < NSYS) s_used[tid] = 0;
  __syncthreads();

  // Gaussian elimination with partial pivoting (no physical row swaps; perm[])
  for (int p = 0; p < NSYS; ++p) {
    if (tid < 64) {
      double best = -1.0; int bi = 0;
      for (int r = tid; r < NSYS; r += 64)
        if (!s_used[r]) { const double a = fabs(M[r][p]); if (a > best) { best = a; bi = r; } }
      for (int o = 32; o > 0; o >>= 1) {
        const double ob = __shfl_down(best, o, 64);
        const int    oi = __shfl_down(bi, o, 64);
        if (ob > best) { best = ob; bi = oi; }
      }
      if (tid == 0) s_piv = bi;
    }
    __syncthreads();
    const int piv = s_piv;
    if (tid == 0) { s_used[piv] = 1; s_perm[p] = piv; }
    __syncthreads();
    const double inv = 1.0 / M[piv][p];
    const int tr = tid & 63, tc = tid >> 6;
    for (int r = tr; r < NSYS; r += 64) {
      if (!s_used[r]) {
        const double m = M[r][p] * inv;
        for (int c = p + 1 + tc; c < NSYS + 2; c += 4)
          M[r][c] -= m * M[piv][c];
      }
    }
    __syncthreads();
  }

  // back substitution (both rhs columns)
  double acc0 = 0.0, acc1 = 0.0;
  const int row = (tid < NSYS) ? s_perm[tid] : 0;
  for (int p = NSYS - 1; p >= 0; --p) {
    if (tid == p) {
      const double d = M[row][p];
      s_xs[0][p] = (M[row][NSYS]     - acc0) / d;
      s_xs[1][p] = (M[row][NSYS + 1] - acc1) / d;
    }
    __syncthreads();
    if (tid < p) {
      const double mp = M[row][p];
      acc0 = fma(mp, s_xs[0][p], acc0);
      acc1 = fma(mp, s_xs[1][p], acc1);
    }
  }
  if (tid < NSYS) {
    ws[WS_WV + (size_t)b * 142 + 2 * tid]     = (float)s_xs[0][tid];
    ws[WS_WV + (size_t)b * 142 + 2 * tid + 1] = (float)s_xs[1][tid];
  }
}

// ------------------------------- K3: fused spline eval + bilinear warp (+norm finalize)
__global__ __launch_bounds__(256) void k3_warp(const float* __restrict__ img,
                                               const float* __restrict__ ws,
                                               float* __restrict__ out) {
  const int bid = blockIdx.x;
  const int b = bid >> 8, y = bid & 255;
  const int tid = threadIdx.x;   // = x

  if (bid == 0 && tid == 0) {
    float s = 0.f;
    for (int i = 0; i < NB; ++i) s += sqrtf(ws[WS_NORM + i]);
    out[OUT_NORM] = s * 0.125f;
  }

  __shared__ float s_c[NP], s_w[NP], s_v[6];
  if (tid < NP) {
    s_c[tid] = ws[WS_DST + b * NP + tid];
    s_w[tid] = ws[WS_WV + (size_t)b * 142 + tid];
  }
  if (tid >= NP && tid < NP + 6) s_v[tid - NP] = ws[WS_WV + (size_t)b * 142 + tid];
  __syncthreads();

  const float yf = (float)y, xf = (float)tid;
  float fy = fmaf(s_v[0], yf, fmaf(s_v[2], xf, s_v[4]));
  float fx = fmaf(s_v[1], yf, fmaf(s_v[3], xf, s_v[5]));
#pragma unroll 4
  for (int l = 0; l < NL; ++l) {
    const float dy = yf - s_c[2 * l];
    const float dx = xf - s_c[2 * l + 1];
    const float r  = fmaf(dy, dy, dx * dx);
    const float ph = 0.5f * r * __logf(fmaxf(r, 1e-10f));
    fy = fmaf(s_w[2 * l],     ph, fy);
    fx = fmaf(s_w[2 * l + 1], ph, fx);
  }

  const float qy = fminf(fmaxf(yf - fy, 0.f), 255.f);
  const float qx = fminf(fmaxf(xf - fx, 0.f), 255.f);
  int y0 = (int)floorf(qy); y0 = y0 > 254 ? 254 : y0;
  int x0 = (int)floorf(qx); x0 = x0 > 254 ? 254 : x0;
  const float wy = qy - (float)y0, wx = qx - (float)x0;
  const float w00 = (1.f - wy) * (1.f - wx), w01 = (1.f - wy) * wx;
  const float w10 = wy * (1.f - wx),         w11 = wy * wx;

  const float* p0 = img + (size_t)b * CIMG * 65536 + y0 * 256 + x0;
  const size_t ob = (size_t)b * CIMG * 65536 + (size_t)y * 256 + tid;
#pragma unroll 4
  for (int c = 0; c < CIMG; ++c) {
    const float* p = p0 + (size_t)c * 65536;
    const float v00 = p[0], v01 = p[1], v10 = p[256], v11 = p[257];
    const float val = fmaf(w00, v00, fmaf(w01, v01, fmaf(w10, v10, w11 * v11)));
    out[ob + (size_t)c * 65536] = val;
  }
}

// ------------------------------------------------------------------ launcher
extern "C" void kernel_launch(void* const* d_in, const int* in_sizes, int n_in,
                              void* d_out, int out_size, void* d_ws, size_t ws_size,
                              hipStream_t stream) {
  const float* x      = (const float*)d_in[0];
  const float* img    = (const float*)d_in[1];
  const float* scales = (const float*)d_in[2];
  const float* lmean  = (const float*)d_in[3];
  const float* W1     = (const float*)d_in[4];
  const float* b1     = (const float*)d_in[5];
  const float* W2     = (const float*)d_in[6];
  const float* b2     = (const float*)d_in[7];
  const float* W3     = (const float*)d_in[8];
  const float* b3     = (const float*)d_in[9];
  float* out = (float*)d_out;
  float* ws  = (float*)d_ws;

  k1_gemv<<<dim3(32, 32), 256, 0, stream>>>(x, W1, ws + WS_PART);
  k2_land_solve<<<NB, 256, 0, stream>>>(ws + WS_PART, scales, lmean, b1, W2, b2, W3, b3, out, ws);
  k3_warp<<<NB * HH, 256, 0, stream>>>(img, ws, out);
}